// Round 3
// baseline (239.555 us; speedup 1.0000x reference)
//
#include <hip/hip_runtime.h>
#include <hip/hip_bf16.h>

// Problem constants (fixed by setup_inputs):
//   bs=8, nq=1500, C=2  -> NI = 12000 rows
//   total_tgt = 4800    -> NJ = 4800 cols
// Output: [NI][NJ] f32 = 230.4 MB  -> write-BW bound (roofline ~37 us @6.3 TB/s).
//
// C[i,j] = softplus(x0)+softplus(x1) - t0*x0 - t1*x1 + 5*(|px-tx|+|py-ty|)
// (uses log_sigmoid(x) - log_sigmoid(-x) = x; the mean-over-2-classes /2
//  cancels against COST_CLASS=2)

#define NI 12000
#define NJ 4800
#define NJF (NJ / 4)      // 1200 float4 per row
#define ROWS 4            // rows per thread in main kernel

// native clang vector (works with __builtin_nontemporal_store, unlike HIP float4)
typedef float f32x4 __attribute__((ext_vector_type(4)));

// ---- precompute: per-row quad (base,-x0,-x1,px) + py, per-target (t0,t1,tx,ty)
__global__ __launch_bounds__(256) void precompute_kernel(
    const float* __restrict__ pred_logits,   // [NI][2]
    const float* __restrict__ pred_points,   // [NI][2]
    const float* __restrict__ tgt_labels,    // [NJ][2]
    const float* __restrict__ tgt_points,    // [NJ][2]
    f32x4* __restrict__ wqa,                 // [NI]
    float* __restrict__ wpy,                 // [NI]
    f32x4* __restrict__ wtgt)                // [NJ]
{
    int tid = blockIdx.x * blockDim.x + threadIdx.x;
    if (tid < NI) {
        float x0 = pred_logits[tid * 2 + 0];
        float x1 = pred_logits[tid * 2 + 1];
        // stable softplus(x) = max(x,0) + log1p(exp(-|x|))
        float sp0 = fmaxf(x0, 0.0f) + log1pf(expf(-fabsf(x0)));
        float sp1 = fmaxf(x1, 0.0f) + log1pf(expf(-fabsf(x1)));
        f32x4 q;
        q.x = sp0 + sp1;                 // base
        q.y = -x0;                       // coeff for t0
        q.z = -x1;                       // coeff for t1
        q.w = pred_points[tid * 2 + 0];  // px
        wqa[tid] = q;
        wpy[tid] = pred_points[tid * 2 + 1];  // py
    } else if (tid < NI + NJ) {
        int j = tid - NI;
        f32x4 t;
        t.x = tgt_labels[j * 2 + 0];
        t.y = tgt_labels[j * 2 + 1];
        t.z = tgt_points[j * 2 + 0];
        t.w = tgt_points[j * 2 + 1];
        wtgt[j] = t;
    }
}

// one output element, all operands in named scalars (register-safe)
__device__ __forceinline__ float cost_elem(f32x4 q, float pyr, f32x4 t) {
    float cc = q.x + q.y * t.x + q.z * t.y;
    float cp = fabsf(q.w - t.z) + fabsf(pyr - t.w);
    return fmaf(5.0f, cp, cc);
}

// ---- main: each thread -> 4 output cols (one f32x4) x ROWS rows.
// Reads are L2-resident (~317 KB working set); stores are the only HBM
// traffic (coalesced 16B/lane = 1 KiB per wave store, nontemporal).
__global__ __launch_bounds__(256) void cmat_kernel(
    const f32x4* __restrict__ wqa,
    const float* __restrict__ wpy,
    const f32x4* __restrict__ wtgt,
    f32x4* __restrict__ out)                 // [NI][NJF]
{
    int jf = blockIdx.x * blockDim.x + threadIdx.x;   // float4-column index
    if (jf >= NJF) return;
    int i0 = blockIdx.y * ROWS;

    // 4 targets for this thread's 4 output columns (64 B contiguous, L2-hot)
    f32x4 t0 = wtgt[jf * 4 + 0];
    f32x4 t1 = wtgt[jf * 4 + 1];
    f32x4 t2 = wtgt[jf * 4 + 2];
    f32x4 t3 = wtgt[jf * 4 + 3];

#pragma unroll
    for (int r = 0; r < ROWS; ++r) {
        f32x4 q   = wqa[i0 + r];   // wave-uniform
        float pyr = wpy[i0 + r];
        f32x4 o;
        o.x = cost_elem(q, pyr, t0);
        o.y = cost_elem(q, pyr, t1);
        o.z = cost_elem(q, pyr, t2);
        o.w = cost_elem(q, pyr, t3);
        __builtin_nontemporal_store(o, &out[(i0 + r) * NJF + jf]);
    }
}

extern "C" void kernel_launch(void* const* d_in, const int* in_sizes, int n_in,
                              void* d_out, int out_size, void* d_ws, size_t ws_size,
                              hipStream_t stream) {
    const float* pred_logits = (const float*)d_in[0];  // 24000
    const float* pred_points = (const float*)d_in[1];  // 24000
    const float* tgt_labels  = (const float*)d_in[2];  // 9600
    const float* tgt_points  = (const float*)d_in[3];  // 9600
    float* out = (float*)d_out;                        // 57,600,000

    // ws layout: wqa [NI] f32x4 | wpy [NI] float | wtgt [NJ] f32x4
    char* ws = (char*)d_ws;
    f32x4* wqa  = (f32x4*)ws;                          // 192,000 B
    float* wpy  = (float*)(ws + NI * sizeof(f32x4));   //  48,000 B
    f32x4* wtgt = (f32x4*)(ws + NI * sizeof(f32x4) + NI * sizeof(float));
    // total ws use: 316,800 B

    dim3 block(256);
    dim3 grid_pre((NI + NJ + 255) / 256);
    precompute_kernel<<<grid_pre, block, 0, stream>>>(
        pred_logits, pred_points, tgt_labels, tgt_points, wqa, wpy, wtgt);

    dim3 grid_main((NJF + 255) / 256, NI / ROWS);   // (5, 3000)
    cmat_kernel<<<grid_main, block, 0, stream>>>(wqa, wpy, wtgt, (f32x4*)out);
}

// Round 6
// 229.014 us; speedup vs baseline: 1.0460x; 1.0460x over previous
//
#include <hip/hip_runtime.h>
#include <hip/hip_bf16.h>

// Problem constants (fixed by setup_inputs):
//   bs=8, nq=1500, C=2  -> NI = 12000 rows
//   total_tgt = 4800    -> NJ = 4800 cols
// Output: [NI][NJ] f32 = 230.4 MB  -> write-BW bound (~37 us @6.3 TB/s).
// NOTE: harness poison-fill of d_out+d_ws (921.6 MB, ~144 us) sits inside
// the timed window — total floor is ~190 us.
//
// C[i,j] = softplus(x0)+softplus(x1) - t0*x0 - t1*x1 + 5*(|px-tx|+|py-ty|)
// (uses log_sigmoid(x) - log_sigmoid(-x) = x; mean-over-2 /2 cancels COST_CLASS=2)

#define NI 12000
#define NJ 4800
#define NJF (NJ / 4)      // 1200 float4 per row
#define ROWS 4            // rows per inner group
#define RITER 5           // row-groups per block -> 20 rows/block

typedef float f32x4 __attribute__((ext_vector_type(4)));

// ---- precompute: per-row quad (base,-x0,-x1,px) + py, per-target (t0,t1,tx,ty)
__global__ __launch_bounds__(256) void precompute_kernel(
    const float* __restrict__ pred_logits,   // [NI][2]
    const float* __restrict__ pred_points,   // [NI][2]
    const float* __restrict__ tgt_labels,    // [NJ][2]
    const float* __restrict__ tgt_points,    // [NJ][2]
    f32x4* __restrict__ wqa,                 // [NI]
    float* __restrict__ wpy,                 // [NI]
    f32x4* __restrict__ wtgt)                // [NJ]
{
    int tid = blockIdx.x * blockDim.x + threadIdx.x;
    if (tid < NI) {
        float x0 = pred_logits[tid * 2 + 0];
        float x1 = pred_logits[tid * 2 + 1];
        // stable softplus(x) = max(x,0) + log1p(exp(-|x|))
        float sp0 = fmaxf(x0, 0.0f) + log1pf(expf(-fabsf(x0)));
        float sp1 = fmaxf(x1, 0.0f) + log1pf(expf(-fabsf(x1)));
        f32x4 q;
        q.x = sp0 + sp1;                 // base
        q.y = -x0;                       // coeff for t0
        q.z = -x1;                       // coeff for t1
        q.w = pred_points[tid * 2 + 0];  // px
        wqa[tid] = q;
        wpy[tid] = pred_points[tid * 2 + 1];  // py
    } else if (tid < NI + NJ) {
        int j = tid - NI;
        f32x4 t;
        t.x = tgt_labels[j * 2 + 0];
        t.y = tgt_labels[j * 2 + 1];
        t.z = tgt_points[j * 2 + 0];
        t.w = tgt_points[j * 2 + 1];
        wtgt[j] = t;
    }
}

__device__ __forceinline__ float cost_elem(f32x4 q, float pyr, f32x4 t) {
    float cc = q.x + q.y * t.x + q.z * t.y;
    float cp = fabsf(q.w - t.z) + fabsf(pyr - t.w);
    return fmaf(5.0f, cp, cc);
}

// ---- main: each thread owns 4 output cols (one f32x4) held-in-register
// targets, loops over 20 rows -> 20 coalesced 16B stores per thread.
// grid (5, NI/(ROWS*RITER)) = (5, 600) = 3000 blocks (~12/CU).
__global__ __launch_bounds__(256) void cmat_kernel(
    const f32x4* __restrict__ wqa,
    const float* __restrict__ wpy,
    const f32x4* __restrict__ wtgt,
    f32x4* __restrict__ out)                 // [NI][NJF]
{
    int jf = blockIdx.x * blockDim.x + threadIdx.x;   // float4-column index
    if (jf >= NJF) return;

    // 4 targets for this thread's 4 output columns, loaded ONCE (L2-hot)
    f32x4 t0 = wtgt[jf * 4 + 0];
    f32x4 t1 = wtgt[jf * 4 + 1];
    f32x4 t2 = wtgt[jf * 4 + 2];
    f32x4 t3 = wtgt[jf * 4 + 3];

    int i00 = blockIdx.y * (ROWS * RITER);
#pragma unroll
    for (int g = 0; g < RITER; ++g) {
#pragma unroll
        for (int r = 0; r < ROWS; ++r) {
            int i = i00 + g * ROWS + r;
            f32x4 q   = wqa[i];   // wave-uniform -> scalar path
            float pyr = wpy[i];
            f32x4 o;
            o.x = cost_elem(q, pyr, t0);
            o.y = cost_elem(q, pyr, t1);
            o.z = cost_elem(q, pyr, t2);
            o.w = cost_elem(q, pyr, t3);
            out[i * NJF + jf] = o;
        }
    }
}

extern "C" void kernel_launch(void* const* d_in, const int* in_sizes, int n_in,
                              void* d_out, int out_size, void* d_ws, size_t ws_size,
                              hipStream_t stream) {
    const float* pred_logits = (const float*)d_in[0];  // 24000
    const float* pred_points = (const float*)d_in[1];  // 24000
    const float* tgt_labels  = (const float*)d_in[2];  // 9600
    const float* tgt_points  = (const float*)d_in[3];  // 9600
    float* out = (float*)d_out;                        // 57,600,000

    // ws layout: wqa [NI] f32x4 | wpy [NI] float | wtgt [NJ] f32x4
    char* ws = (char*)d_ws;
    f32x4* wqa  = (f32x4*)ws;                          // 192,000 B
    float* wpy  = (float*)(ws + NI * sizeof(f32x4));   //  48,000 B
    f32x4* wtgt = (f32x4*)(ws + NI * sizeof(f32x4) + NI * sizeof(float));
    // total ws use: 316,800 B

    dim3 block(256);
    dim3 grid_pre((NI + NJ + 255) / 256);
    precompute_kernel<<<grid_pre, block, 0, stream>>>(
        pred_logits, pred_points, tgt_labels, tgt_points, wqa, wpy, wtgt);

    dim3 grid_main((NJF + 255) / 256, NI / (ROWS * RITER));   // (5, 600)
    cmat_kernel<<<grid_main, block, 0, stream>>>(wqa, wpy, wtgt, (f32x4*)out);
}